// Round 3
// baseline (26.150 us; speedup 1.0000x reference)
//
#include <hip/hip_runtime.h>

// x: (N=64, C=3, W=16, T=128, V=25, M=2) fp32, row-major
// strides (elems): N:307200, C:102400, W:6400, T:50, V:2, M:1
// b = ((n*T+t)*V+v)*M+m ; local = t*50+v*2+m == b % 6400 (bijective, order-preserving)
// Reference: permute(0,3,4,5,2,1) -> (...,W,C) block, flat i = w_orig*3 + c_orig,
// then view as (C=3,W=16): xr[c][w] = elem i = c*16+w -> (c_orig,w_orig) = (i%3, i/3).
// Thread handles 4 consecutive b (same n since 6400%4==0): float4 loads.
// Single-pass moments: cov = (Sxy - 16*mx*my)/15.
// out: (B,4,4) fp32, B = 409600

__global__ void __launch_bounds__(256)
gaussian_embed_kernel(const float* __restrict__ x, float* __restrict__ out, int B4) {
    int t = blockIdx.x * blockDim.x + threadIdx.x;
    if (t >= B4) return;
    const int b   = t << 2;
    const int n   = b / 6400;
    const int rem = b - n * 6400;
    // float4-unit strides: c_orig: 102400/4=25600, w_orig: 6400/4=1600
    const float4* __restrict__ xb = (const float4*)(x + (size_t)n * 307200 + rem);

    float s0[4] = {0,0,0,0}, s1[4] = {0,0,0,0}, s2[4] = {0,0,0,0};
    float p00[4] = {0,0,0,0}, p01[4] = {0,0,0,0}, p02[4] = {0,0,0,0};
    float p11[4] = {0,0,0,0}, p12[4] = {0,0,0,0}, p22[4] = {0,0,0,0};

#pragma unroll
    for (int w = 0; w < 16; ++w) {
        // xr row r, column w  <->  flat i = r*16 + w  <->  offset (i%3)*25600 + (i/3)*1600
        const int i0 = w, i1 = w + 16, i2 = w + 32;
        const float4 av = xb[(i0 % 3) * 25600 + (i0 / 3) * 1600];
        const float4 bv = xb[(i1 % 3) * 25600 + (i1 / 3) * 1600];
        const float4 cv = xb[(i2 % 3) * 25600 + (i2 / 3) * 1600];
        const float a[4]  = {av.x, av.y, av.z, av.w};
        const float bb[4] = {bv.x, bv.y, bv.z, bv.w};
        const float cc[4] = {cv.x, cv.y, cv.z, cv.w};
#pragma unroll
        for (int j = 0; j < 4; ++j) {
            s0[j]  += a[j];          s1[j]  += bb[j];          s2[j]  += cc[j];
            p00[j] += a[j] * a[j];   p01[j] += a[j] * bb[j];   p02[j] += a[j] * cc[j];
            p11[j] += bb[j] * bb[j]; p12[j] += bb[j] * cc[j];  p22[j] += cc[j] * cc[j];
        }
    }

#pragma unroll
    for (int j = 0; j < 4; ++j) {
        const float m0 = s0[j] * 0.0625f, m1 = s1[j] * 0.0625f, m2 = s2[j] * 0.0625f;
        const float inv15 = 1.f / 15.f;
        const float c00 = (p00[j] - 16.f * m0 * m0) * inv15;
        const float c01 = (p01[j] - 16.f * m0 * m1) * inv15;
        const float c02 = (p02[j] - 16.f * m0 * m2) * inv15;
        const float c11 = (p11[j] - 16.f * m1 * m1) * inv15;
        const float c12 = (p12[j] - 16.f * m1 * m2) * inv15;
        const float c22 = (p22[j] - 16.f * m2 * m2) * inv15;

        const float tr    = c00 + c11 + c22;
        const float invtr = 1.f / tr;
        const float diag  = 0.001f * tr;
        const float a  = c00 * invtr + diag;
        const float bq = c01 * invtr;
        const float cq = c02 * invtr;
        const float d  = c11 * invtr + diag;
        const float e  = c12 * invtr;
        const float g  = c22 * invtr + diag;

        const float det = a * (d * g - e * e) - bq * (bq * g - cq * e) + cq * (bq * e - cq * d);
        const float dsp = rsqrtf(sqrtf(det));  // det^(-1/4)

        const float om01 = dsp * (bq + m0 * m1);
        const float om02 = dsp * (cq + m0 * m2);
        const float om12 = dsp * (e + m1 * m2);
        const float dm0 = dsp * m0, dm1 = dsp * m1, dm2 = dsp * m2;

        float4* __restrict__ o = (float4*)(out + (size_t)(b + j) * 16);
        o[0] = make_float4(dsp * (a + m0 * m0), om01, om02, dm0);
        o[1] = make_float4(om01, dsp * (d + m1 * m1), om12, dm1);
        o[2] = make_float4(om02, om12, dsp * (g + m2 * m2), dm2);
        o[3] = make_float4(dm0, dm1, dm2, dsp);
    }
}

extern "C" void kernel_launch(void* const* d_in, const int* in_sizes, int n_in,
                              void* d_out, int out_size, void* d_ws, size_t ws_size,
                              hipStream_t stream) {
    const float* x = (const float*)d_in[0];
    float* out = (float*)d_out;
    const int B  = in_sizes[0] / 48;  // 409600
    const int B4 = B / 4;             // 102400
    const int threads = 256;
    const int blocks = (B4 + threads - 1) / threads;  // 400
    gaussian_embed_kernel<<<blocks, threads, 0, stream>>>(x, out, B4);
}

// Round 4
// 21.980 us; speedup vs baseline: 1.1897x; 1.1897x over previous
//
#include <hip/hip_runtime.h>

// x: (N=64, C=3, W=16, T=128, V=25, M=2) fp32, row-major
// strides (elems): N:307200, C:102400, W:6400, T:50, V:2, M:1
// b = ((n*T+t)*V+v)*M+m ; local = t*50+v*2+m == b % 6400 (bijective, order-preserving)
// xr[c][w] = flat elem i = c*16+w of the permuted (W,C) block -> (c_orig,w_orig)=(i%3,i/3)
// Thread handles 4 consecutive b (same n since 6400%4==0): float4 loads (1KB/instr/wave).
// Single-pass moments: cov = (Sxy - 16*mx*my)/15.
// Epilogue: stage 64KB block output in LDS (XOR-swizzled), then lane-contiguous
// float4 stores (1KB/instr) -- fixes the 64B-stride partial-line store scatter.
// out: (B,4,4) fp32, B = 409600.  Grid exact: 400 blocks x 256 threads.

__global__ void __launch_bounds__(256)
gaussian_embed_kernel(const float* __restrict__ x, float* __restrict__ out) {
    __shared__ float4 lds[4096];  // 256 threads * 16 float4 = 64KB

    const int t  = threadIdx.x;
    const int tb = blockIdx.x * 256 + t;
    const int b  = tb << 2;
    const int n   = b / 6400;
    const int rem = b - n * 6400;
    // float4-unit strides: c_orig: 102400/4=25600, w_orig: 6400/4=1600
    const float4* __restrict__ xb = (const float4*)(x + (size_t)n * 307200 + rem);

    float s0[4] = {0,0,0,0}, s1[4] = {0,0,0,0}, s2[4] = {0,0,0,0};
    float p00[4] = {0,0,0,0}, p01[4] = {0,0,0,0}, p02[4] = {0,0,0,0};
    float p11[4] = {0,0,0,0}, p12[4] = {0,0,0,0}, p22[4] = {0,0,0,0};

#pragma unroll
    for (int w = 0; w < 16; ++w) {
        // xr row r, col w <-> flat i = r*16 + w <-> f4 offset (i%3)*25600 + (i/3)*1600
        const int i0 = w, i1 = w + 16, i2 = w + 32;
        const float4 av = xb[(i0 % 3) * 25600 + (i0 / 3) * 1600];
        const float4 bv = xb[(i1 % 3) * 25600 + (i1 / 3) * 1600];
        const float4 cv = xb[(i2 % 3) * 25600 + (i2 / 3) * 1600];
        const float a[4]  = {av.x, av.y, av.z, av.w};
        const float bb[4] = {bv.x, bv.y, bv.z, bv.w};
        const float cc[4] = {cv.x, cv.y, cv.z, cv.w};
#pragma unroll
        for (int j = 0; j < 4; ++j) {
            s0[j]  += a[j];          s1[j]  += bb[j];          s2[j]  += cc[j];
            p00[j] += a[j] * a[j];   p01[j] += a[j] * bb[j];   p02[j] += a[j] * cc[j];
            p11[j] += bb[j] * bb[j]; p12[j] += bb[j] * cc[j];  p22[j] += cc[j] * cc[j];
        }
    }

#pragma unroll
    for (int j = 0; j < 4; ++j) {
        const float m0 = s0[j] * 0.0625f, m1 = s1[j] * 0.0625f, m2 = s2[j] * 0.0625f;
        const float inv15 = 1.f / 15.f;
        const float c00 = (p00[j] - 16.f * m0 * m0) * inv15;
        const float c01 = (p01[j] - 16.f * m0 * m1) * inv15;
        const float c02 = (p02[j] - 16.f * m0 * m2) * inv15;
        const float c11 = (p11[j] - 16.f * m1 * m1) * inv15;
        const float c12 = (p12[j] - 16.f * m1 * m2) * inv15;
        const float c22 = (p22[j] - 16.f * m2 * m2) * inv15;

        const float tr    = c00 + c11 + c22;
        const float invtr = 1.f / tr;
        const float diag  = 0.001f * tr;
        const float a  = c00 * invtr + diag;
        const float bq = c01 * invtr;
        const float cq = c02 * invtr;
        const float d  = c11 * invtr + diag;
        const float e  = c12 * invtr;
        const float g  = c22 * invtr + diag;

        const float det = a * (d * g - e * e) - bq * (bq * g - cq * e) + cq * (bq * e - cq * d);
        const float dsp = rsqrtf(sqrtf(det));  // det^(-1/4)

        const float om01 = dsp * (bq + m0 * m1);
        const float om02 = dsp * (cq + m0 * m2);
        const float om12 = dsp * (e + m1 * m2);
        const float dm0 = dsp * m0, dm1 = dsp * m1, dm2 = dsp * m2;

        // Stage 4 rows (float4 each) into LDS, XOR-swizzled: slot k = j*4 + row
        const int base = t * 16;
        const int sw   = t & 15;
        lds[base + ((j * 4 + 0) ^ sw)] = make_float4(dsp * (a + m0 * m0), om01, om02, dm0);
        lds[base + ((j * 4 + 1) ^ sw)] = make_float4(om01, dsp * (d + m1 * m1), om12, dm1);
        lds[base + ((j * 4 + 2) ^ sw)] = make_float4(om02, om12, dsp * (g + m2 * m2), dm2);
        lds[base + ((j * 4 + 3) ^ sw)] = make_float4(dm0, dm1, dm2, dsp);
    }

    __syncthreads();

    // Coalesced block store: block covers 4096 float4 (64KB) contiguous
    float4* __restrict__ o = (float4*)out + (size_t)blockIdx.x * 4096;
#pragma unroll
    for (int k2 = 0; k2 < 16; ++k2) {
        const int g  = k2 * 256 + t;
        const int ts = g >> 4;
        const int it = g & 15;
        o[g] = lds[ts * 16 + (it ^ (ts & 15))];
    }
}

extern "C" void kernel_launch(void* const* d_in, const int* in_sizes, int n_in,
                              void* d_out, int out_size, void* d_ws, size_t ws_size,
                              hipStream_t stream) {
    const float* x = (const float*)d_in[0];
    float* out = (float*)d_out;
    const int B  = in_sizes[0] / 48;  // 409600
    const int B4 = B / 4;             // 102400
    const int threads = 256;
    const int blocks = B4 / threads;  // 400 exact (no tail; syncthreads-safe)
    gaussian_embed_kernel<<<blocks, threads, 0, stream>>>(x, out);
}

// Round 5
// 21.617 us; speedup vs baseline: 1.2097x; 1.0168x over previous
//
#include <hip/hip_runtime.h>

// x: (N=64, C=3, W=16, T=128, V=25, M=2) fp32, row-major
// strides (elems): N:307200, C:102400, W:6400, T:50, V:2, M:1
// b = ((n*T+t)*V+v)*M+m ; local = t*50+v*2+m == b % 6400 (bijective, order-preserving)
// xr[c][w] = flat elem i = c*16+w of permuted (W,C) block -> (c_orig,w_orig)=(i%3,i/3)
// Thread handles 2 consecutive b (same n since 6400%2==0): float2 loads (512B/instr/wave).
// 2b/thread (not 4) => 3200 waves = 12.5/CU for latency hiding (R4 had 6.25/CU: stalls).
// Single-pass moments: cov = (Sxy - 16*mx*my)/15.
// Epilogue: stage 16KB block output in LDS (XOR-swizzled), lane-contiguous float4 stores.
// out: (B,4,4) fp32, B = 409600.  Grid exact: 1600 blocks x 128 threads.

__global__ void __launch_bounds__(128)
gaussian_embed_kernel(const float* __restrict__ x, float* __restrict__ out) {
    __shared__ float4 lds[1024];  // 128 threads * 8 float4 = 16KB

    const int t  = threadIdx.x;
    const int tb = blockIdx.x * 128 + t;
    const int b  = tb << 1;
    const int n   = b / 6400;
    const int rem = b - n * 6400;
    // float2-unit strides: c_orig: 102400/2=51200, w_orig: 6400/2=3200
    const float2* __restrict__ xb = (const float2*)(x + (size_t)n * 307200 + rem);

    float s0[2] = {0,0}, s1[2] = {0,0}, s2[2] = {0,0};
    float p00[2] = {0,0}, p01[2] = {0,0}, p02[2] = {0,0};
    float p11[2] = {0,0}, p12[2] = {0,0}, p22[2] = {0,0};

#pragma unroll
    for (int w = 0; w < 16; ++w) {
        // xr row r, col w <-> flat i = r*16 + w <-> f2 offset (i%3)*51200 + (i/3)*3200
        const int i0 = w, i1 = w + 16, i2 = w + 32;
        const float2 av = xb[(i0 % 3) * 51200 + (i0 / 3) * 3200];
        const float2 bv = xb[(i1 % 3) * 51200 + (i1 / 3) * 3200];
        const float2 cv = xb[(i2 % 3) * 51200 + (i2 / 3) * 3200];
        const float a[2]  = {av.x, av.y};
        const float bb[2] = {bv.x, bv.y};
        const float cc[2] = {cv.x, cv.y};
#pragma unroll
        for (int j = 0; j < 2; ++j) {
            s0[j]  += a[j];          s1[j]  += bb[j];          s2[j]  += cc[j];
            p00[j] += a[j] * a[j];   p01[j] += a[j] * bb[j];   p02[j] += a[j] * cc[j];
            p11[j] += bb[j] * bb[j]; p12[j] += bb[j] * cc[j];  p22[j] += cc[j] * cc[j];
        }
    }

#pragma unroll
    for (int j = 0; j < 2; ++j) {
        const float m0 = s0[j] * 0.0625f, m1 = s1[j] * 0.0625f, m2 = s2[j] * 0.0625f;
        const float inv15 = 1.f / 15.f;
        const float c00 = (p00[j] - 16.f * m0 * m0) * inv15;
        const float c01 = (p01[j] - 16.f * m0 * m1) * inv15;
        const float c02 = (p02[j] - 16.f * m0 * m2) * inv15;
        const float c11 = (p11[j] - 16.f * m1 * m1) * inv15;
        const float c12 = (p12[j] - 16.f * m1 * m2) * inv15;
        const float c22 = (p22[j] - 16.f * m2 * m2) * inv15;

        const float tr    = c00 + c11 + c22;
        const float invtr = 1.f / tr;
        const float diag  = 0.001f * tr;
        const float a  = c00 * invtr + diag;
        const float bq = c01 * invtr;
        const float cq = c02 * invtr;
        const float d  = c11 * invtr + diag;
        const float e  = c12 * invtr;
        const float g  = c22 * invtr + diag;

        const float det = a * (d * g - e * e) - bq * (bq * g - cq * e) + cq * (bq * e - cq * d);
        const float dsp = rsqrtf(sqrtf(det));  // det^(-1/4)

        const float om01 = dsp * (bq + m0 * m1);
        const float om02 = dsp * (cq + m0 * m2);
        const float om12 = dsp * (e + m1 * m2);
        const float dm0 = dsp * m0, dm1 = dsp * m1, dm2 = dsp * m2;

        // Stage 4 rows (float4 each) into LDS, XOR-swizzled: slot = j*4 + row
        const int base = t * 8;
        const int sw   = t & 7;
        lds[base + ((j * 4 + 0) ^ sw)] = make_float4(dsp * (a + m0 * m0), om01, om02, dm0);
        lds[base + ((j * 4 + 1) ^ sw)] = make_float4(om01, dsp * (d + m1 * m1), om12, dm1);
        lds[base + ((j * 4 + 2) ^ sw)] = make_float4(om02, om12, dsp * (g + m2 * m2), dm2);
        lds[base + ((j * 4 + 3) ^ sw)] = make_float4(dm0, dm1, dm2, dsp);
    }

    __syncthreads();

    // Coalesced block store: block covers 1024 float4 (16KB) contiguous
    float4* __restrict__ o = (float4*)out + (size_t)blockIdx.x * 1024;
#pragma unroll
    for (int k2 = 0; k2 < 8; ++k2) {
        const int g  = k2 * 128 + t;
        const int ts = g >> 3;
        const int it = g & 7;
        o[g] = lds[ts * 8 + (it ^ (ts & 7))];
    }
}

extern "C" void kernel_launch(void* const* d_in, const int* in_sizes, int n_in,
                              void* d_out, int out_size, void* d_ws, size_t ws_size,
                              hipStream_t stream) {
    const float* x = (const float*)d_in[0];
    float* out = (float*)d_out;
    const int B  = in_sizes[0] / 48;  // 409600
    const int B2 = B / 2;             // 204800 threads
    const int threads = 128;
    const int blocks = B2 / threads;  // 1600 exact (no tail; syncthreads-safe)
    gaussian_embed_kernel<<<blocks, threads, 0, stream>>>(x, out);
}

// Round 6
// 21.432 us; speedup vs baseline: 1.2201x; 1.0087x over previous
//
#include <hip/hip_runtime.h>

// x: (N=64, C=3, W=16, T=128, V=25, M=2) fp32, row-major
// strides (elems): N:307200, C:102400, W:6400, T:50, V:2, M:1
// b = ((n*T+t)*V+v)*M+m ; local = t*50+v*2+m == b % 6400 (bijective, order-preserving)
// xr[c][w] = flat elem i = c*16+w of permuted (W,C) block -> (c_orig,w_orig)=(i%3,i/3)
// Thread handles 2 consecutive b (same n, 6400%2==0): float2 loads (512B/instr/wave).
// KEY (R6): issue ALL 48 loads into registers BEFORE compute -- fused load+FMA
// (R3-R5) let the compiler insert vmcnt waits each iter (~3 loads in flight);
// load-all-first keeps ~24KB/wave in flight (R1 evidence: its reads were fastest).
// Single-pass moments: cov = (Sxy - 16*mx*my)/15.
// Epilogue: stage 16KB block output in LDS (XOR-swizzled), lane-contiguous float4 stores.
// out: (B,4,4) fp32, B = 409600.  Grid exact: 1600 blocks x 128 threads.

__global__ void __launch_bounds__(128)
gaussian_embed_kernel(const float* __restrict__ x, float* __restrict__ out) {
    __shared__ float4 lds[1024];  // 128 threads * 8 float4 = 16KB

    const int t  = threadIdx.x;
    const int tb = blockIdx.x * 128 + t;
    const int b  = tb << 1;
    const int n   = b / 6400;
    const int rem = b - n * 6400;
    // float2-unit strides: c_orig: 102400/2=51200, w_orig: 6400/2=3200
    const float2* __restrict__ xb = (const float2*)(x + (size_t)n * 307200 + rem);

    // ---- Phase 1: issue all 48 loads back-to-back (grouped by w = consume order)
    float2 rr[16][3];
#pragma unroll
    for (int w = 0; w < 16; ++w) {
#pragma unroll
        for (int c = 0; c < 3; ++c) {
            const int i = c * 16 + w;  // flat xr index
            rr[w][c] = xb[(i % 3) * 51200 + (i / 3) * 3200];
        }
    }

    // ---- Phase 2: single-pass moments (consumes rr in load order)
    float s0[2] = {0,0}, s1[2] = {0,0}, s2[2] = {0,0};
    float p00[2] = {0,0}, p01[2] = {0,0}, p02[2] = {0,0};
    float p11[2] = {0,0}, p12[2] = {0,0}, p22[2] = {0,0};
#pragma unroll
    for (int w = 0; w < 16; ++w) {
        const float a[2]  = {rr[w][0].x, rr[w][0].y};
        const float bb[2] = {rr[w][1].x, rr[w][1].y};
        const float cc[2] = {rr[w][2].x, rr[w][2].y};
#pragma unroll
        for (int j = 0; j < 2; ++j) {
            s0[j]  += a[j];          s1[j]  += bb[j];          s2[j]  += cc[j];
            p00[j] += a[j] * a[j];   p01[j] += a[j] * bb[j];   p02[j] += a[j] * cc[j];
            p11[j] += bb[j] * bb[j]; p12[j] += bb[j] * cc[j];  p22[j] += cc[j] * cc[j];
        }
    }

    // ---- Phase 3: epilogue per b
#pragma unroll
    for (int j = 0; j < 2; ++j) {
        const float m0 = s0[j] * 0.0625f, m1 = s1[j] * 0.0625f, m2 = s2[j] * 0.0625f;
        const float inv15 = 1.f / 15.f;
        const float c00 = (p00[j] - 16.f * m0 * m0) * inv15;
        const float c01 = (p01[j] - 16.f * m0 * m1) * inv15;
        const float c02 = (p02[j] - 16.f * m0 * m2) * inv15;
        const float c11 = (p11[j] - 16.f * m1 * m1) * inv15;
        const float c12 = (p12[j] - 16.f * m1 * m2) * inv15;
        const float c22 = (p22[j] - 16.f * m2 * m2) * inv15;

        const float tr    = c00 + c11 + c22;
        const float invtr = 1.f / tr;
        const float diag  = 0.001f * tr;
        const float a  = c00 * invtr + diag;
        const float bq = c01 * invtr;
        const float cq = c02 * invtr;
        const float d  = c11 * invtr + diag;
        const float e  = c12 * invtr;
        const float g  = c22 * invtr + diag;

        const float det = a * (d * g - e * e) - bq * (bq * g - cq * e) + cq * (bq * e - cq * d);
        const float dsp = rsqrtf(sqrtf(det));  // det^(-1/4)

        const float om01 = dsp * (bq + m0 * m1);
        const float om02 = dsp * (cq + m0 * m2);
        const float om12 = dsp * (e + m1 * m2);
        const float dm0 = dsp * m0, dm1 = dsp * m1, dm2 = dsp * m2;

        // Stage 4 rows (float4 each) into LDS, XOR-swizzled: slot = j*4 + row
        const int base = t * 8;
        const int sw   = t & 7;
        lds[base + ((j * 4 + 0) ^ sw)] = make_float4(dsp * (a + m0 * m0), om01, om02, dm0);
        lds[base + ((j * 4 + 1) ^ sw)] = make_float4(om01, dsp * (d + m1 * m1), om12, dm1);
        lds[base + ((j * 4 + 2) ^ sw)] = make_float4(om02, om12, dsp * (g + m2 * m2), dm2);
        lds[base + ((j * 4 + 3) ^ sw)] = make_float4(dm0, dm1, dm2, dsp);
    }

    __syncthreads();

    // ---- Phase 4: coalesced block store (block covers 1024 float4 = 16KB contiguous)
    float4* __restrict__ o = (float4*)out + (size_t)blockIdx.x * 1024;
#pragma unroll
    for (int k2 = 0; k2 < 8; ++k2) {
        const int g  = k2 * 128 + t;
        const int ts = g >> 3;
        const int it = g & 7;
        o[g] = lds[ts * 8 + (it ^ (ts & 7))];
    }
}

extern "C" void kernel_launch(void* const* d_in, const int* in_sizes, int n_in,
                              void* d_out, int out_size, void* d_ws, size_t ws_size,
                              hipStream_t stream) {
    const float* x = (const float*)d_in[0];
    float* out = (float*)d_out;
    const int B  = in_sizes[0] / 48;  // 409600
    const int B2 = B / 2;             // 204800 threads
    const int threads = 128;
    const int blocks = B2 / threads;  // 1600 exact (no tail; syncthreads-safe)
    gaussian_embed_kernel<<<blocks, threads, 0, stream>>>(x, out);
}